// Round 2
// baseline (194.526 us; speedup 1.0000x reference)
//
#include <hip/hip_runtime.h>

#define EPS 1e-5f

typedef _Float16 f16x8 __attribute__((ext_vector_type(8)));
typedef _Float16 f16x4 __attribute__((ext_vector_type(4)));
typedef float f32x4 __attribute__((ext_vector_type(4)));

// ---- workspace layout (float offsets) ----
#define XT_OFF    0u          // 256*1024 fp32
#define ACT1_OFF  262144u     // f16 196*1024*16
#define ACT2_OFF  1867776u    // f16 144*1024*32
#define ACT3_OFF  4227072u    // f16 100*1024*64
#define W2H_OFF   7503872u    // f16 144*5*32*32
#define W3H_OFF   7872512u    // f16 100*9*64*32
#define FP_OFF    9598976u    // fp32 100*10*1024
#define ACC_OFF   10622976u   // fp32 224: s1(16) q1(16) s2(32) q2(32) s3(64) q3(64)

// ---------------- prep: W2/W3 convert + x transpose + zero stat accumulators ----------------
__global__ __launch_bounds__(256) void k_prep(const float* __restrict__ W2,
                                              const float* __restrict__ W3,
                                              const float* __restrict__ x,
                                              _Float16* __restrict__ W2h,
                                              _Float16* __restrict__ W3h,
                                              float* __restrict__ xT,
                                              float* __restrict__ acc) {
    int gb = blockIdx.x, tid = threadIdx.x;
    __shared__ float tile[16][17];
    if (gb >= 10080) {
        // transpose x (1024,256) -> xT (256,1024), 16x16 tiles
        int t = gb - 10080;
        int tx = tid & 15, ty = tid >> 4;
        int p0 = (t & 15) * 16, b0 = (t >> 4) * 16;
        tile[ty][tx] = x[(b0 + ty) * 256 + p0 + tx];
        __syncthreads();
        xT[(p0 + ty) * 1024 + b0 + tx] = tile[tx][ty];
        return;
    }
    if (gb == 0 && tid < 224) acc[tid] = 0.f;
    int idx = gb * 256 + tid;
    if (idx < 737280) {
        int k = idx & 31, o = (idx >> 5) & 31, rest = idx >> 10;
        int t = rest % 5, p = rest / 5;
        int pos = 2 * t + (k >> 4), c = k & 15;
        float v = (pos < 9) ? W2[((o * 16 + c) * 144 + p) * 9 + pos] : 0.f;
        W2h[idx] = (_Float16)v;
    } else {
        int jdx = idx - 737280;
        if (jdx < 1843200) {
            int c = jdx & 31, o = (jdx >> 5) & 63, rest = jdx >> 11;
            int pos = rest % 9, p = rest / 9;
            W3h[jdx] = (_Float16)W3[((o * 32 + c) * 100 + p) * 9 + pos];
        }
    }
}

// ---------------- LC1 (fp32 math): xT -> act1h f16 [p][b][c16] RAW; block stats -> atomicAdd acc1 ----------------
__global__ __launch_bounds__(256) void k_lc1(const float* __restrict__ xT,
                                             const float* __restrict__ W1,
                                             const float* __restrict__ b1,
                                             _Float16* __restrict__ act1h,
                                             float* __restrict__ acc1) {   // s[16] q[16]
    int p = blockIdx.x;              // 0..195
    int i = p / 14, j = p % 14;
    int tid = threadIdx.x;
    int b = blockIdx.y * 256 + tid;
    __shared__ float wS[144], bS[16];
    __shared__ float red[256 * 33];  // [thread][32 vals], pad 33 -> conflict-free
    __shared__ float pp[4 * 33];
    if (tid < 144) { int o = tid / 9, k = tid % 9; wS[tid] = W1[(o * 196 + p) * 9 + k]; }
    if (tid < 16) bS[tid] = b1[tid * 196 + p];
    __syncthreads();
    float xv[9];
#pragma unroll
    for (int di = 0; di < 3; di++)
#pragma unroll
        for (int dj = 0; dj < 3; dj++)
            xv[di * 3 + dj] = xT[((i + di) * 16 + (j + dj)) * 1024 + b];
    float accv[16];
#pragma unroll
    for (int o = 0; o < 16; o++) {
        float acc = bS[o];
#pragma unroll
        for (int k = 0; k < 9; k++) acc += wS[o * 9 + k] * xv[k];
        accv[o] = acc;
    }
    f16x8 lo, hi;
#pragma unroll
    for (int e = 0; e < 8; e++) { lo[e] = (_Float16)accv[e]; hi[e] = (_Float16)accv[8 + e]; }
    _Float16* dst = act1h + ((size_t)(p * 1024 + b)) * 16;
    *(f16x8*)dst = lo;
    *(f16x8*)(dst + 8) = hi;
    // ---- block-level stat reduction (s rows 0..15, q rows 16..31) ----
#pragma unroll
    for (int o = 0; o < 16; o++) {
        red[tid * 33 + o] = accv[o];
        red[tid * 33 + 16 + o] = accv[o] * accv[o];
    }
    __syncthreads();
    {
        int w = tid >> 6, lane = tid & 63, v = lane & 31, h = lane >> 5;
        int rbase = w * 64 + h * 32;
        float ssum = 0.f;
#pragma unroll
        for (int k = 0; k < 32; k++) ssum += red[(rbase + k) * 33 + v];
        ssum += __shfl_down(ssum, 32);
        if (h == 0) pp[w * 33 + v] = ssum;
    }
    __syncthreads();
    if (tid < 32) {
        float t4 = pp[tid] + pp[33 + tid] + pp[66 + tid] + pp[99 + tid];
        atomicAdd(acc1 + tid, t4);
    }
}

// ---------------- BN apply in place: act = relu(a*act + c), fp32 math ----------------
// acc holds raw sums s[C], q[C]; one f16x8 vector per thread, perfectly coalesced.
__global__ __launch_bounds__(256) void k_bn(_Float16* __restrict__ act,
                                            const float* __restrict__ acc,
                                            const float* __restrict__ g,
                                            const float* __restrict__ be,
                                            int C, int nvec, float invN) {
    __shared__ float aS[64], cS[64];
    int tid = threadIdx.x;
    if (tid < C) {
        float s = acc[tid], q = acc[C + tid];
        float m = s * invN, var = q * invN - m * m;
        float r = rsqrtf(var + EPS);
        float av = g[tid] * r;
        aS[tid] = av; cS[tid] = be[tid] - m * av;
    }
    __syncthreads();
    int idx = blockIdx.x * 256 + tid;
    if (idx >= nvec) return;
    int cg = idx & ((C >> 3) - 1);       // which channel-group of 8
    f16x8 x = *((f16x8*)act + idx);
    f16x8 y;
#pragma unroll
    for (int e = 0; e < 8; e++) {
        float v = fmaf(aS[cg * 8 + e], (float)x[e], cS[cg * 8 + e]);
        y[e] = (_Float16)(v > 0.f ? v : 0.f);
    }
    *((f16x8*)act + idx) = y;
}

// ---------------- LC2 MFMA: normalized act1h -> act2h RAW; block stats -> atomicAdd acc2 ----------------
__global__ __launch_bounds__(256) void k_lc2m(const _Float16* __restrict__ act1h,
                                              const _Float16* __restrict__ W2h,
                                              const float* __restrict__ b2,
                                              _Float16* __restrict__ act2h,
                                              float* __restrict__ acc2) {      // s[32] q[32]
    int p = blockIdx.x, i = p / 12, j = p % 12;
    int tid = threadIdx.x, wv = tid >> 6, lane = tid & 63, n = lane & 15, quad = lane >> 4;
    int bbase = blockIdx.y * 128 + wv * 32;
    f32x4 acc[2][2] = {};
#pragma unroll
    for (int t = 0; t < 5; t++) {
        int pos0 = 2 * t, pos1 = (2 * t + 1 < 9) ? 2 * t + 1 : 8;
        int mypos = (quad >> 1) ? pos1 : pos0;
        int ip = (i + mypos / 3) * 14 + (j + mypos % 3);
        f16x8 bfr[2];
#pragma unroll
        for (int nt = 0; nt < 2; nt++)
            bfr[nt] = *(const f16x8*)(act1h + ((size_t)(ip * 1024 + bbase + nt * 16 + n)) * 16 + (quad & 1) * 8);
        f16x8 afr[2];
#pragma unroll
        for (int ot = 0; ot < 2; ot++)
            afr[ot] = *(const f16x8*)(W2h + ((size_t)((p * 5 + t) * 32 + ot * 16 + n)) * 32 + quad * 8);
#pragma unroll
        for (int ot = 0; ot < 2; ot++)
#pragma unroll
            for (int nt = 0; nt < 2; nt++)
                acc[ot][nt] = __builtin_amdgcn_mfma_f32_16x16x32_f16(afr[ot], bfr[nt], acc[ot][nt], 0, 0, 0);
    }
    float s_[8] = {}, q_[8] = {};
#pragma unroll
    for (int ot = 0; ot < 2; ot++) {
        float bias[4];
#pragma unroll
        for (int r = 0; r < 4; r++) bias[r] = b2[(ot * 16 + quad * 4 + r) * 144 + p];
#pragma unroll
        for (int nt = 0; nt < 2; nt++) {
            int b = bbase + nt * 16 + n;
            f16x4 st;
#pragma unroll
            for (int r = 0; r < 4; r++) {
                float v = acc[ot][nt][r] + bias[r];
                st[r] = (_Float16)v;
                s_[ot * 4 + r] += v; q_[ot * 4 + r] += v * v;
            }
            *(f16x4*)(act2h + ((size_t)(p * 1024 + b)) * 32 + ot * 16 + quad * 4) = st;
        }
    }
    // ---- block-level stat reduction: rows v=2*o+isq, 64 contributions (wv*16+n) ----
    __shared__ float red[64 * 65];
#pragma unroll
    for (int u = 0; u < 8; u++) {
        int o = (u >> 2) * 16 + quad * 4 + (u & 3);
        red[(2 * o) * 65 + wv * 16 + n] = s_[u];
        red[(2 * o + 1) * 65 + wv * 16 + n] = q_[u];
    }
    __syncthreads();
    if (tid < 64) {
        const float* row = red + tid * 65;
        float t0 = 0.f;
#pragma unroll
        for (int c = 0; c < 64; c++) t0 += row[c];
        atomicAdd(acc2 + (tid & 1) * 32 + (tid >> 1), t0);
    }
}

// ---------------- LC3 MFMA: normalized act2h -> act3h RAW; block stats -> atomicAdd acc3 ----------------
__global__ __launch_bounds__(256) void k_lc3m(const _Float16* __restrict__ act2h,
                                              const _Float16* __restrict__ W3h,
                                              const float* __restrict__ b3,
                                              _Float16* __restrict__ act3h,
                                              float* __restrict__ acc3) {      // s[64] q[64]
    int p = blockIdx.x, i = p / 10, j = p % 10;
    int tid = threadIdx.x, wv = tid >> 6, lane = tid & 63, n = lane & 15, quad = lane >> 4;
    int bbase = blockIdx.y * 128 + wv * 32;
    f32x4 acc[4][2] = {};
#pragma unroll
    for (int pos = 0; pos < 9; pos++) {
        int ip = (i + pos / 3) * 12 + (j + pos % 3);
        f16x8 bfr[2];
#pragma unroll
        for (int nt = 0; nt < 2; nt++)
            bfr[nt] = *(const f16x8*)(act2h + ((size_t)(ip * 1024 + bbase + nt * 16 + n)) * 32 + quad * 8);
        f16x8 afr[4];
#pragma unroll
        for (int ot = 0; ot < 4; ot++)
            afr[ot] = *(const f16x8*)(W3h + ((size_t)((p * 9 + pos) * 64 + ot * 16 + n)) * 32 + quad * 8);
#pragma unroll
        for (int ot = 0; ot < 4; ot++)
#pragma unroll
            for (int nt = 0; nt < 2; nt++)
                acc[ot][nt] = __builtin_amdgcn_mfma_f32_16x16x32_f16(afr[ot], bfr[nt], acc[ot][nt], 0, 0, 0);
    }
    float s_[16] = {}, q_[16] = {};
#pragma unroll
    for (int ot = 0; ot < 4; ot++) {
        float bias[4];
#pragma unroll
        for (int r = 0; r < 4; r++) bias[r] = b3[(ot * 16 + quad * 4 + r) * 100 + p];
#pragma unroll
        for (int nt = 0; nt < 2; nt++) {
            int b = bbase + nt * 16 + n;
            f16x4 st;
#pragma unroll
            for (int r = 0; r < 4; r++) {
                float v = acc[ot][nt][r] + bias[r];
                st[r] = (_Float16)v;
                s_[ot * 4 + r] += v; q_[ot * 4 + r] += v * v;
            }
            *(f16x4*)(act3h + ((size_t)(p * 1024 + b)) * 64 + ot * 16 + quad * 4) = st;
        }
    }
    // ---- block-level stat reduction: 128 rows (v=2*o+isq), 64 contributions ----
    __shared__ float red[128 * 65];
#pragma unroll
    for (int u = 0; u < 16; u++) {
        int o = (u >> 2) * 16 + quad * 4 + (u & 3);
        red[(2 * o) * 65 + wv * 16 + n] = s_[u];
        red[(2 * o + 1) * 65 + wv * 16 + n] = q_[u];
    }
    __syncthreads();
    if (tid < 128) {
        const float* row = red + tid * 65;
        float t0 = 0.f;
#pragma unroll
        for (int c = 0; c < 64; c++) t0 += row[c];
        atomicAdd(acc3 + (tid & 1) * 64 + (tid >> 1), t0);
    }
}

// ---------------- FC: tanh(BN3(act3h)) @ fcW^T -> partials [p][jj][b] ----------------
// act3 is read exactly once per element, so BN3+tanh stays fused here (no redundancy).
__global__ __launch_bounds__(256) void k_fc(const _Float16* __restrict__ act3h,
                                            const float* __restrict__ fcW,
                                            const float* __restrict__ acc3,  // s[64] q[64]
                                            const float* __restrict__ g3,
                                            const float* __restrict__ be3,
                                            float* __restrict__ fpart) {
    int p = blockIdx.y;
    int tid = threadIdx.x;
    int b = blockIdx.x * 256 + tid;
    __shared__ float wS[640], aS[64], cS[64];
    for (int idx = tid; idx < 640; idx += 256) {
        int o = idx / 10, jj = idx % 10;
        wS[idx] = fcW[jj * 6400 + o * 100 + p];
    }
    if (tid < 64) {
        const float invN3 = 1.f / (1024.f * 100.f);
        float s = acc3[tid], q = acc3[64 + tid];
        float m = s * invN3, var = q * invN3 - m * m;
        float r = rsqrtf(var + EPS);
        float av = g3[tid] * r;
        aS[tid] = av; cS[tid] = be3[tid] - m * av;
    }
    __syncthreads();
    float acc[10];
#pragma unroll
    for (int jj = 0; jj < 10; jj++) acc[jj] = 0.f;
    const _Float16* src = act3h + ((size_t)(p * 1024 + b)) * 64;
    for (int o8 = 0; o8 < 8; o8++) {
        f16x8 xv = *(const f16x8*)(src + o8 * 8);
#pragma unroll
        for (int e = 0; e < 8; e++) {
            int o = o8 * 8 + e;
            float v = fmaf(aS[o], (float)xv[e], cS[o]);
            float e2 = __expf(2.f * v);
            v = 1.f - 2.f / (e2 + 1.f);   // tanh, safe at +/-inf
#pragma unroll
            for (int jj = 0; jj < 10; jj++) acc[jj] = fmaf(wS[o * 10 + jj], v, acc[jj]);
        }
    }
#pragma unroll
    for (int jj = 0; jj < 10; jj++) fpart[((size_t)p * 10 + jj) * 1024 + b] = acc[jj];
}

// ---------------- reduce fc partials + bias -> out ----------------
__global__ __launch_bounds__(256) void k_fc_reduce(const float* __restrict__ fpart,
                                                   const float* __restrict__ fcb,
                                                   float* __restrict__ out) {
    int idx = blockIdx.x * 256 + threadIdx.x;  // jj*1024 + b
    int jj = idx >> 10, b = idx & 1023;
    float acc = fcb[jj];
    for (int p = 0; p < 100; p++) acc += fpart[(p * 10 + jj) * 1024 + b];
    out[b * 10 + jj] = acc;
}

extern "C" void kernel_launch(void* const* d_in, const int* in_sizes, int n_in,
                              void* d_out, int out_size, void* d_ws, size_t ws_size,
                              hipStream_t stream) {
    const float* x   = (const float*)d_in[0];
    const float* W1  = (const float*)d_in[1];
    const float* b1  = (const float*)d_in[2];
    const float* g1  = (const float*)d_in[3];
    const float* be1 = (const float*)d_in[4];
    const float* W2  = (const float*)d_in[5];
    const float* b2  = (const float*)d_in[6];
    const float* g2  = (const float*)d_in[7];
    const float* be2 = (const float*)d_in[8];
    const float* W3  = (const float*)d_in[9];
    const float* b3  = (const float*)d_in[10];
    const float* g3  = (const float*)d_in[11];
    const float* be3 = (const float*)d_in[12];
    const float* fcW = (const float*)d_in[13];
    const float* fcb = (const float*)d_in[14];
    float* out = (float*)d_out;
    float* ws = (float*)d_ws;

    float* xT    = ws + XT_OFF;
    _Float16* act1h = (_Float16*)(ws + ACT1_OFF);
    _Float16* act2h = (_Float16*)(ws + ACT2_OFF);
    _Float16* act3h = (_Float16*)(ws + ACT3_OFF);
    _Float16* W2h   = (_Float16*)(ws + W2H_OFF);
    _Float16* W3h   = (_Float16*)(ws + W3H_OFF);
    float* fp   = ws + FP_OFF;
    float* acc  = ws + ACC_OFF;

    k_prep<<<11104, 256, 0, stream>>>(W2, W3, x, W2h, W3h, xT, acc);
    k_lc1<<<dim3(196, 4), 256, 0, stream>>>(xT, W1, b1, act1h, acc);
    k_bn<<<1568, 256, 0, stream>>>(act1h, acc, g1, be1, 16, 401408, 1.f / (1024.f * 196.f));
    k_lc2m<<<dim3(144, 8), 256, 0, stream>>>(act1h, W2h, b2, act2h, acc + 32);
    k_bn<<<2304, 256, 0, stream>>>(act2h, acc + 32, g2, be2, 32, 589824, 1.f / (1024.f * 144.f));
    k_lc3m<<<dim3(100, 8), 256, 0, stream>>>(act2h, W3h, b3, act3h, acc + 96);
    k_fc<<<dim3(4, 100), 256, 0, stream>>>(act3h, fcW, acc + 96, g3, be3, fp);
    k_fc_reduce<<<40, 256, 0, stream>>>(fp, fcb, out);
}

// Round 3
// 160.666 us; speedup vs baseline: 1.2107x; 1.2107x over previous
//
#include <hip/hip_runtime.h>

#define EPS 1e-5f

typedef _Float16 f16x8 __attribute__((ext_vector_type(8)));
typedef _Float16 f16x4 __attribute__((ext_vector_type(4)));
typedef float f32x4 __attribute__((ext_vector_type(4)));

// ---- workspace layout (float offsets) ----
#define XT_OFF    0u          // 256*1024 fp32
#define ACT1_OFF  262144u     // f16 196*1024*16
#define ACT2_OFF  1867776u    // f16 144*1024*32
#define ACT3_OFF  4227072u    // f16 100*1024*64
#define W2H_OFF   7503872u    // f16 144*10*512 = 737,280 halves  [p][pos10][o32][c16], pos9 zero
#define W3H_OFF   7872512u    // f16 900*2048  = 1,843,200 halves [p*9+pos][o64][c32]
#define FP_OFF    9598976u    // fp32 100*10*1024
#define ACC_OFF   10622976u   // fp32 224: s1(16) q1(16) s2(32) q2(32) s3(64) q3(64)

// ---------------- prep: coalesced LDS-tiled transposes + acc zero ----------------
// W2: src matrix (oc=512) x (ppos=1296), dst [p*10+pos][oc]  (pos plane 9 zeroed)
// W3: src matrix (oc=2048) x (ppos=900), dst [ppos][oc]  (identical layout to consumer's old one)
// x : (1024,256) -> xT (256,1024)
__global__ __launch_bounds__(256) void k_prep(const float* __restrict__ W2,
                                              const float* __restrict__ W3,
                                              const float* __restrict__ x,
                                              _Float16* __restrict__ W2h,
                                              _Float16* __restrict__ W3h,
                                              float* __restrict__ xT,
                                              float* __restrict__ acc) {
    int gb = blockIdx.x, tid = threadIdx.x;
    __shared__ float tile[32][33];
    int tx = tid & 31, ty = tid >> 5;                 // 32 x 8
    if (gb < 656) {
        // ---- W2 transpose: tiles 16 (rows) x 41 (cols) ----
        int tR = gb / 41, tC = gb % 41;
        int oc0 = tR * 32, pp0 = tC * 32;
#pragma unroll
        for (int r = 0; r < 4; r++) {
            int col = pp0 + tx;
            if (col < 1296) tile[ty + 8 * r][tx] = W2[(size_t)(oc0 + ty + 8 * r) * 1296 + col];
        }
        __syncthreads();
#pragma unroll
        for (int r = 0; r < 4; r++) {
            int pr = pp0 + ty + 8 * r;
            if (pr < 1296) {
                int p = pr / 9, pos = pr - 9 * p;
                W2h[(size_t)(p * 10 + pos) * 512 + oc0 + tx] = (_Float16)tile[tx][ty + 8 * r];
            }
        }
        return;
    }
    if (gb < 692) {
        // ---- zero plane pos=9 of W2h (144*512 halves) + acc zero ----
        if (gb == 656 && tid < 224) acc[tid] = 0.f;
        int idx = (gb - 656) * 256 + tid;             // 0..9215
        int p = idx >> 6, ocv = idx & 63;
        f16x8 z = {(_Float16)0.f, (_Float16)0.f, (_Float16)0.f, (_Float16)0.f,
                   (_Float16)0.f, (_Float16)0.f, (_Float16)0.f, (_Float16)0.f};
        *(f16x8*)(W2h + (size_t)(p * 10 + 9) * 512 + ocv * 8) = z;
        return;
    }
    if (gb < 2548) {
        // ---- W3 transpose: tiles 64 (rows) x 29 (cols) ----
        int t = gb - 692;
        int tR = t / 29, tC = t % 29;
        int oc0 = tR * 32, pp0 = tC * 32;
#pragma unroll
        for (int r = 0; r < 4; r++) {
            int col = pp0 + tx;
            if (col < 900) tile[ty + 8 * r][tx] = W3[(size_t)(oc0 + ty + 8 * r) * 900 + col];
        }
        __syncthreads();
#pragma unroll
        for (int r = 0; r < 4; r++) {
            int pr = pp0 + ty + 8 * r;
            if (pr < 900) W3h[(size_t)pr * 2048 + oc0 + tx] = (_Float16)tile[tx][ty + 8 * r];
        }
        return;
    }
    {
        // ---- x transpose: 1024 tiles of 16x16 ----
        int t = gb - 2548;
        float* t17 = &tile[0][0];                     // use as [16][17]
        int tx4 = tid & 15, ty4 = tid >> 4;
        int p0 = (t & 15) * 16, b0 = (t >> 4) * 16;
        t17[ty4 * 17 + tx4] = x[(b0 + ty4) * 256 + p0 + tx4];
        __syncthreads();
        xT[(p0 + ty4) * 1024 + b0 + tx4] = t17[tx4 * 17 + ty4];
    }
}

// ---------------- LC1 (fp32 math): xT -> act1h f16 [p][b][c16] RAW; block stats -> atomicAdd acc1 ----------------
__global__ __launch_bounds__(256) void k_lc1(const float* __restrict__ xT,
                                             const float* __restrict__ W1,
                                             const float* __restrict__ b1,
                                             _Float16* __restrict__ act1h,
                                             float* __restrict__ acc1) {   // s[16] q[16]
    int p = blockIdx.x;              // 0..195
    int i = p / 14, j = p % 14;
    int tid = threadIdx.x;
    int b = blockIdx.y * 256 + tid;
    __shared__ float wS[144], bS[16];
    __shared__ float red[256 * 33];  // [thread][32 vals], pad 33 -> conflict-free
    __shared__ float pp[4 * 33];
    if (tid < 144) { int o = tid / 9, k = tid % 9; wS[tid] = W1[(o * 196 + p) * 9 + k]; }
    if (tid < 16) bS[tid] = b1[tid * 196 + p];
    __syncthreads();
    float xv[9];
#pragma unroll
    for (int di = 0; di < 3; di++)
#pragma unroll
        for (int dj = 0; dj < 3; dj++)
            xv[di * 3 + dj] = xT[((i + di) * 16 + (j + dj)) * 1024 + b];
    float accv[16];
#pragma unroll
    for (int o = 0; o < 16; o++) {
        float acc = bS[o];
#pragma unroll
        for (int k = 0; k < 9; k++) acc += wS[o * 9 + k] * xv[k];
        accv[o] = acc;
    }
    f16x8 lo, hi;
#pragma unroll
    for (int e = 0; e < 8; e++) { lo[e] = (_Float16)accv[e]; hi[e] = (_Float16)accv[8 + e]; }
    _Float16* dst = act1h + ((size_t)(p * 1024 + b)) * 16;
    *(f16x8*)dst = lo;
    *(f16x8*)(dst + 8) = hi;
    // ---- block-level stat reduction (s rows 0..15, q rows 16..31) ----
#pragma unroll
    for (int o = 0; o < 16; o++) {
        red[tid * 33 + o] = accv[o];
        red[tid * 33 + 16 + o] = accv[o] * accv[o];
    }
    __syncthreads();
    {
        int w = tid >> 6, lane = tid & 63, v = lane & 31, h = lane >> 5;
        int rbase = w * 64 + h * 32;
        float ssum = 0.f;
#pragma unroll
        for (int k = 0; k < 32; k++) ssum += red[(rbase + k) * 33 + v];
        ssum += __shfl_down(ssum, 32);
        if (h == 0) pp[w * 33 + v] = ssum;
    }
    __syncthreads();
    if (tid < 32) {
        float t4 = pp[tid] + pp[33 + tid] + pp[66 + tid] + pp[99 + tid];
        atomicAdd(acc1 + tid, t4);
    }
}

// ---------------- LC2 MFMA: act1h (+BN1/ReLU on read) -> act2h RAW; stats -> atomicAdd acc2 ----------------
// grid (144, 4); wave: o32 x b64 (nt=4); weights reused across nt
__global__ __launch_bounds__(256) void k_lc2m(const _Float16* __restrict__ act1h,
                                              const _Float16* __restrict__ W2h,
                                              const float* __restrict__ b2,
                                              const float* __restrict__ acc1,  // s[16] q[16]
                                              const float* __restrict__ g1,
                                              const float* __restrict__ be1,
                                              _Float16* __restrict__ act2h,
                                              float* __restrict__ acc2) {      // s[32] q[32]
    int p = blockIdx.x, i = p / 12, j = p % 12;
    int tid = threadIdx.x, wv = tid >> 6, lane = tid & 63, n = lane & 15, quad = lane >> 4;
    int bbase = blockIdx.y * 256 + wv * 64;
    const float invN1 = 1.f / (1024.f * 196.f);
    f16x8 a8, c8;
#pragma unroll
    for (int e = 0; e < 8; e++) {
        int ch = (quad & 1) * 8 + e;
        float s = acc1[ch], q = acc1[16 + ch];
        float m = s * invN1, var = q * invN1 - m * m;
        float r = rsqrtf(var + EPS);
        float av = g1[ch] * r;
        a8[e] = (_Float16)av;
        c8[e] = (_Float16)(be1[ch] - m * av);
    }
    f32x4 acc[2][4] = {};
#pragma unroll
    for (int t = 0; t < 5; t++) {
        int posA = 2 * t + (quad >> 1);         // 0..9 ; 9 hits W2h zero plane
        int posB = posA > 8 ? 8 : posA;         // B reads pos8 (A slot is zero)
        int ip = (i + posB / 3) * 14 + (j + posB % 3);
        f16x8 afr[2];
#pragma unroll
        for (int ot = 0; ot < 2; ot++)
            afr[ot] = *(const f16x8*)(W2h + (size_t)(p * 10 + posA) * 512 + (ot * 16 + n) * 16 + (quad & 1) * 8);
#pragma unroll
        for (int nt = 0; nt < 4; nt++) {
            f16x8 xv = *(const f16x8*)(act1h + ((size_t)(ip * 1024 + bbase + nt * 16 + n)) * 16 + (quad & 1) * 8);
#pragma unroll
            for (int e = 0; e < 8; e++) {
                _Float16 v = xv[e] * a8[e] + c8[e];
                xv[e] = v > (_Float16)0.f ? v : (_Float16)0.f;
            }
#pragma unroll
            for (int ot = 0; ot < 2; ot++)
                acc[ot][nt] = __builtin_amdgcn_mfma_f32_16x16x32_f16(afr[ot], xv, acc[ot][nt], 0, 0, 0);
        }
    }
    float s_[8] = {}, q_[8] = {};
#pragma unroll
    for (int ot = 0; ot < 2; ot++) {
        float bias[4];
#pragma unroll
        for (int r = 0; r < 4; r++) bias[r] = b2[(ot * 16 + quad * 4 + r) * 144 + p];
#pragma unroll
        for (int nt = 0; nt < 4; nt++) {
            int b = bbase + nt * 16 + n;
            f16x4 st;
#pragma unroll
            for (int r = 0; r < 4; r++) {
                float v = acc[ot][nt][r] + bias[r];
                st[r] = (_Float16)v;
                s_[ot * 4 + r] += v; q_[ot * 4 + r] += v * v;
            }
            *(f16x4*)(act2h + ((size_t)(p * 1024 + b)) * 32 + ot * 16 + quad * 4) = st;
        }
    }
    __shared__ float red[64 * 65];
#pragma unroll
    for (int u = 0; u < 8; u++) {
        int o = (u >> 2) * 16 + quad * 4 + (u & 3);
        red[(2 * o) * 65 + wv * 16 + n] = s_[u];
        red[(2 * o + 1) * 65 + wv * 16 + n] = q_[u];
    }
    __syncthreads();
    if (tid < 64) {
        const float* row = red + tid * 65;
        float t0 = 0.f;
#pragma unroll
        for (int c = 0; c < 64; c++) t0 += row[c];
        atomicAdd(acc2 + (tid & 1) * 32 + (tid >> 1), t0);
    }
}

// ---------------- LC3 MFMA: act2h (+BN2/ReLU on read) -> act3h RAW; stats -> atomicAdd acc3 ----------------
// grid (100, 4); wave: o64 x b64 (nt=4)
__global__ __launch_bounds__(256) void k_lc3m(const _Float16* __restrict__ act2h,
                                              const _Float16* __restrict__ W3h,
                                              const float* __restrict__ b3,
                                              const float* __restrict__ acc2,  // s[32] q[32]
                                              const float* __restrict__ g2,
                                              const float* __restrict__ be2,
                                              _Float16* __restrict__ act3h,
                                              float* __restrict__ acc3) {      // s[64] q[64]
    int p = blockIdx.x, i = p / 10, j = p % 10;
    int tid = threadIdx.x, wv = tid >> 6, lane = tid & 63, n = lane & 15, quad = lane >> 4;
    int bbase = blockIdx.y * 256 + wv * 64;
    const float invN2 = 1.f / (1024.f * 144.f);
    f16x8 a8, c8;
#pragma unroll
    for (int e = 0; e < 8; e++) {
        int ch = quad * 8 + e;
        float s = acc2[ch], q = acc2[32 + ch];
        float m = s * invN2, var = q * invN2 - m * m;
        float r = rsqrtf(var + EPS);
        float av = g2[ch] * r;
        a8[e] = (_Float16)av;
        c8[e] = (_Float16)(be2[ch] - m * av);
    }
    f32x4 acc[4][4] = {};
#pragma unroll
    for (int pos = 0; pos < 9; pos++) {
        int ip = (i + pos / 3) * 12 + (j + pos % 3);
        f16x8 afr[4];
#pragma unroll
        for (int ot = 0; ot < 4; ot++)
            afr[ot] = *(const f16x8*)(W3h + (size_t)(p * 9 + pos) * 2048 + (ot * 16 + n) * 32 + quad * 8);
#pragma unroll
        for (int nt = 0; nt < 4; nt++) {
            f16x8 xv = *(const f16x8*)(act2h + ((size_t)(ip * 1024 + bbase + nt * 16 + n)) * 32 + quad * 8);
#pragma unroll
            for (int e = 0; e < 8; e++) {
                _Float16 v = xv[e] * a8[e] + c8[e];
                xv[e] = v > (_Float16)0.f ? v : (_Float16)0.f;
            }
#pragma unroll
            for (int ot = 0; ot < 4; ot++)
                acc[ot][nt] = __builtin_amdgcn_mfma_f32_16x16x32_f16(afr[ot], xv, acc[ot][nt], 0, 0, 0);
        }
    }
    float s_[16] = {}, q_[16] = {};
#pragma unroll
    for (int ot = 0; ot < 4; ot++) {
        float bias[4];
#pragma unroll
        for (int r = 0; r < 4; r++) bias[r] = b3[(ot * 16 + quad * 4 + r) * 100 + p];
#pragma unroll
        for (int nt = 0; nt < 4; nt++) {
            int b = bbase + nt * 16 + n;
            f16x4 st;
#pragma unroll
            for (int r = 0; r < 4; r++) {
                float v = acc[ot][nt][r] + bias[r];
                st[r] = (_Float16)v;
                s_[ot * 4 + r] += v; q_[ot * 4 + r] += v * v;
            }
            *(f16x4*)(act3h + ((size_t)(p * 1024 + b)) * 64 + ot * 16 + quad * 4) = st;
        }
    }
    __shared__ float red[128 * 65];
#pragma unroll
    for (int u = 0; u < 16; u++) {
        int o = (u >> 2) * 16 + quad * 4 + (u & 3);
        red[(2 * o) * 65 + wv * 16 + n] = s_[u];
        red[(2 * o + 1) * 65 + wv * 16 + n] = q_[u];
    }
    __syncthreads();
    if (tid < 128) {
        const float* row = red + tid * 65;
        float t0 = 0.f;
#pragma unroll
        for (int c = 0; c < 64; c++) t0 += row[c];
        atomicAdd(acc3 + (tid & 1) * 64 + (tid >> 1), t0);
    }
}

// ---------------- FC: tanh(BN3(act3h)) @ fcW^T -> partials [p][jj][b] ----------------
__global__ __launch_bounds__(256) void k_fc(const _Float16* __restrict__ act3h,
                                            const float* __restrict__ fcW,
                                            const float* __restrict__ acc3,  // s[64] q[64]
                                            const float* __restrict__ g3,
                                            const float* __restrict__ be3,
                                            float* __restrict__ fpart) {
    int p = blockIdx.y;
    int tid = threadIdx.x;
    int b = blockIdx.x * 256 + tid;
    __shared__ float wS[640], aS[64], cS[64];
    for (int idx = tid; idx < 640; idx += 256) {
        int o = idx / 10, jj = idx % 10;
        wS[idx] = fcW[jj * 6400 + o * 100 + p];
    }
    if (tid < 64) {
        const float invN3 = 1.f / (1024.f * 100.f);
        float s = acc3[tid], q = acc3[64 + tid];
        float m = s * invN3, var = q * invN3 - m * m;
        float r = rsqrtf(var + EPS);
        float av = g3[tid] * r;
        aS[tid] = av; cS[tid] = be3[tid] - m * av;
    }
    __syncthreads();
    float acc[10];
#pragma unroll
    for (int jj = 0; jj < 10; jj++) acc[jj] = 0.f;
    const _Float16* src = act3h + ((size_t)(p * 1024 + b)) * 64;
    for (int o8 = 0; o8 < 8; o8++) {
        f16x8 xv = *(const f16x8*)(src + o8 * 8);
#pragma unroll
        for (int e = 0; e < 8; e++) {
            int o = o8 * 8 + e;
            float v = fmaf(aS[o], (float)xv[e], cS[o]);
            float e2 = __expf(2.f * v);
            v = 1.f - 2.f / (e2 + 1.f);   // tanh, safe at +/-inf
#pragma unroll
            for (int jj = 0; jj < 10; jj++) acc[jj] = fmaf(wS[o * 10 + jj], v, acc[jj]);
        }
    }
#pragma unroll
    for (int jj = 0; jj < 10; jj++) fpart[((size_t)p * 10 + jj) * 1024 + b] = acc[jj];
}

// ---------------- reduce fc partials + bias -> out ----------------
__global__ __launch_bounds__(256) void k_fc_reduce(const float* __restrict__ fpart,
                                                   const float* __restrict__ fcb,
                                                   float* __restrict__ out) {
    int idx = blockIdx.x * 256 + threadIdx.x;  // jj*1024 + b
    int jj = idx >> 10, b = idx & 1023;
    float acc = fcb[jj];
    for (int p = 0; p < 100; p++) acc += fpart[(p * 10 + jj) * 1024 + b];
    out[b * 10 + jj] = acc;
}

extern "C" void kernel_launch(void* const* d_in, const int* in_sizes, int n_in,
                              void* d_out, int out_size, void* d_ws, size_t ws_size,
                              hipStream_t stream) {
    const float* x   = (const float*)d_in[0];
    const float* W1  = (const float*)d_in[1];
    const float* b1  = (const float*)d_in[2];
    const float* g1  = (const float*)d_in[3];
    const float* be1 = (const float*)d_in[4];
    const float* W2  = (const float*)d_in[5];
    const float* b2  = (const float*)d_in[6];
    const float* g2  = (const float*)d_in[7];
    const float* be2 = (const float*)d_in[8];
    const float* W3  = (const float*)d_in[9];
    const float* b3  = (const float*)d_in[10];
    const float* g3  = (const float*)d_in[11];
    const float* be3 = (const float*)d_in[12];
    const float* fcW = (const float*)d_in[13];
    const float* fcb = (const float*)d_in[14];
    float* out = (float*)d_out;
    float* ws = (float*)d_ws;

    float* xT    = ws + XT_OFF;
    _Float16* act1h = (_Float16*)(ws + ACT1_OFF);
    _Float16* act2h = (_Float16*)(ws + ACT2_OFF);
    _Float16* act3h = (_Float16*)(ws + ACT3_OFF);
    _Float16* W2h   = (_Float16*)(ws + W2H_OFF);
    _Float16* W3h   = (_Float16*)(ws + W3H_OFF);
    float* fp   = ws + FP_OFF;
    float* acc  = ws + ACC_OFF;

    k_prep<<<3572, 256, 0, stream>>>(W2, W3, x, W2h, W3h, xT, acc);
    k_lc1<<<dim3(196, 4), 256, 0, stream>>>(xT, W1, b1, act1h, acc);
    k_lc2m<<<dim3(144, 4), 256, 0, stream>>>(act1h, W2h, b2, acc, g1, be1, act2h, acc + 32);
    k_lc3m<<<dim3(100, 4), 256, 0, stream>>>(act2h, W3h, b3, acc + 32, g2, be2, act3h, acc + 96);
    k_fc<<<dim3(4, 100), 256, 0, stream>>>(act3h, fcW, acc + 96, g3, be3, fp);
    k_fc_reduce<<<40, 256, 0, stream>>>(fp, fcb, out);
}

// Round 4
// 159.896 us; speedup vs baseline: 1.2166x; 1.0048x over previous
//
#include <hip/hip_runtime.h>

#define EPS 1e-5f

typedef _Float16 f16x8 __attribute__((ext_vector_type(8)));
typedef _Float16 f16x4 __attribute__((ext_vector_type(4)));
typedef float f32x4 __attribute__((ext_vector_type(4)));

// ---- workspace layout (float offsets) ----
#define XT_OFF    0u          // 256*1024 fp32
#define ACT1_OFF  262144u     // f16 196*1024*16
#define ACT2_OFF  1867776u    // f16 144*1024*32
#define ACT3_OFF  4227072u    // f16 100*1024*64
#define W2H_OFF   7503872u    // f16 144*10*512 = 737,280 halves  [p][pos10][o32][c16], pos9 zero
#define W3H_OFF   7872512u    // f16 900*2048  = 1,843,200 halves [p*9+pos][o64][c32]
#define FP_OFF    9598976u    // fp32 100*10*1024
#define ACC_OFF   10622976u   // fp32 224: s1(16) q1(16) s2(32) q2(32) s3(64) q3(64)

// ---------------- prep: coalesced LDS-tiled transposes + acc zero ----------------
__global__ __launch_bounds__(256) void k_prep(const float* __restrict__ W2,
                                              const float* __restrict__ W3,
                                              const float* __restrict__ x,
                                              _Float16* __restrict__ W2h,
                                              _Float16* __restrict__ W3h,
                                              float* __restrict__ xT,
                                              float* __restrict__ acc) {
    int gb = blockIdx.x, tid = threadIdx.x;
    __shared__ float tile[32][33];
    int tx = tid & 31, ty = tid >> 5;                 // 32 x 8
    if (gb < 656) {
        // ---- W2 transpose: tiles 16 (rows) x 41 (cols) ----
        int tR = gb / 41, tC = gb % 41;
        int oc0 = tR * 32, pp0 = tC * 32;
#pragma unroll
        for (int r = 0; r < 4; r++) {
            int col = pp0 + tx;
            if (col < 1296) tile[ty + 8 * r][tx] = W2[(size_t)(oc0 + ty + 8 * r) * 1296 + col];
        }
        __syncthreads();
#pragma unroll
        for (int r = 0; r < 4; r++) {
            int pr = pp0 + ty + 8 * r;
            if (pr < 1296) {
                int p = pr / 9, pos = pr - 9 * p;
                W2h[(size_t)(p * 10 + pos) * 512 + oc0 + tx] = (_Float16)tile[tx][ty + 8 * r];
            }
        }
        return;
    }
    if (gb < 692) {
        // ---- zero plane pos=9 of W2h (144*512 halves) + acc zero ----
        if (gb == 656 && tid < 224) acc[tid] = 0.f;
        int idx = (gb - 656) * 256 + tid;             // 0..9215
        int p = idx >> 6, ocv = idx & 63;
        f16x8 z = {(_Float16)0.f, (_Float16)0.f, (_Float16)0.f, (_Float16)0.f,
                   (_Float16)0.f, (_Float16)0.f, (_Float16)0.f, (_Float16)0.f};
        *(f16x8*)(W2h + (size_t)(p * 10 + 9) * 512 + ocv * 8) = z;
        return;
    }
    if (gb < 2548) {
        // ---- W3 transpose: tiles 64 (rows) x 29 (cols) ----
        int t = gb - 692;
        int tR = t / 29, tC = t % 29;
        int oc0 = tR * 32, pp0 = tC * 32;
#pragma unroll
        for (int r = 0; r < 4; r++) {
            int col = pp0 + tx;
            if (col < 900) tile[ty + 8 * r][tx] = W3[(size_t)(oc0 + ty + 8 * r) * 900 + col];
        }
        __syncthreads();
#pragma unroll
        for (int r = 0; r < 4; r++) {
            int pr = pp0 + ty + 8 * r;
            if (pr < 900) W3h[(size_t)pr * 2048 + oc0 + tx] = (_Float16)tile[tx][ty + 8 * r];
        }
        return;
    }
    {
        // ---- x transpose: 1024 tiles of 16x16 ----
        int t = gb - 2548;
        float* t17 = &tile[0][0];                     // use as [16][17]
        int tx4 = tid & 15, ty4 = tid >> 4;
        int p0 = (t & 15) * 16, b0 = (t >> 4) * 16;
        t17[ty4 * 17 + tx4] = x[(b0 + ty4) * 256 + p0 + tx4];
        __syncthreads();
        xT[(p0 + ty4) * 1024 + b0 + tx4] = t17[tx4 * 17 + ty4];
    }
}

// ---------------- LC1 (fp32 math): xT -> act1h f16 [p][b][c16] RAW; block stats -> atomicAdd acc1 ----------------
// grid: 784 blocks 1-D, XCD-contiguous swizzle (784 = 8*98)
__global__ __launch_bounds__(256) void k_lc1(const float* __restrict__ xT,
                                             const float* __restrict__ W1,
                                             const float* __restrict__ b1,
                                             _Float16* __restrict__ act1h,
                                             float* __restrict__ acc1) {   // s[16] q[16]
    int bid = blockIdx.x;
    int wg = (bid & 7) * 98 + (bid >> 3);   // XCD j owns wg in [j*98, (j+1)*98)
    int p = wg >> 2;                        // 0..195, contiguous per XCD
    int i = p / 14, j = p % 14;
    int tid = threadIdx.x;
    int b = (wg & 3) * 256 + tid;
    __shared__ float wS[144], bS[16];
    __shared__ float red[256 * 33];  // [thread][32 vals], pad 33 -> conflict-free
    __shared__ float pp[4 * 33];
    if (tid < 144) { int o = tid / 9, k = tid % 9; wS[tid] = W1[(o * 196 + p) * 9 + k]; }
    if (tid < 16) bS[tid] = b1[tid * 196 + p];
    __syncthreads();
    float xv[9];
#pragma unroll
    for (int di = 0; di < 3; di++)
#pragma unroll
        for (int dj = 0; dj < 3; dj++)
            xv[di * 3 + dj] = xT[((i + di) * 16 + (j + dj)) * 1024 + b];
    float accv[16];
#pragma unroll
    for (int o = 0; o < 16; o++) {
        float acc = bS[o];
#pragma unroll
        for (int k = 0; k < 9; k++) acc += wS[o * 9 + k] * xv[k];
        accv[o] = acc;
    }
    f16x8 lo, hi;
#pragma unroll
    for (int e = 0; e < 8; e++) { lo[e] = (_Float16)accv[e]; hi[e] = (_Float16)accv[8 + e]; }
    _Float16* dst = act1h + ((size_t)(p * 1024 + b)) * 16;
    *(f16x8*)dst = lo;
    *(f16x8*)(dst + 8) = hi;
    // ---- block-level stat reduction (s rows 0..15, q rows 16..31) ----
#pragma unroll
    for (int o = 0; o < 16; o++) {
        red[tid * 33 + o] = accv[o];
        red[tid * 33 + 16 + o] = accv[o] * accv[o];
    }
    __syncthreads();
    {
        int w = tid >> 6, lane = tid & 63, v = lane & 31, h = lane >> 5;
        int rbase = w * 64 + h * 32;
        float ssum = 0.f;
#pragma unroll
        for (int k = 0; k < 32; k++) ssum += red[(rbase + k) * 33 + v];
        ssum += __shfl_down(ssum, 32);
        if (h == 0) pp[w * 33 + v] = ssum;
    }
    __syncthreads();
    if (tid < 32) {
        float t4 = pp[tid] + pp[33 + tid] + pp[66 + tid] + pp[99 + tid];
        atomicAdd(acc1 + tid, t4);
    }
}

// ---------------- LC2 MFMA: act1h (+BN1/ReLU on read) -> act2h RAW; stats -> atomicAdd acc2 ----------------
// grid: 576 blocks 1-D, XCD swizzle (576 = 8*72 -> 18 contiguous p per XCD; act1 halo ~2.1MB fits 4MB L2)
__global__ __launch_bounds__(256) void k_lc2m(const _Float16* __restrict__ act1h,
                                              const _Float16* __restrict__ W2h,
                                              const float* __restrict__ b2,
                                              const float* __restrict__ acc1,  // s[16] q[16]
                                              const float* __restrict__ g1,
                                              const float* __restrict__ be1,
                                              _Float16* __restrict__ act2h,
                                              float* __restrict__ acc2) {      // s[32] q[32]
    int bid = blockIdx.x;
    int wg = (bid & 7) * 72 + (bid >> 3);
    int p = wg >> 2, i = p / 12, j = p % 12;
    int tid = threadIdx.x, wv = tid >> 6, lane = tid & 63, n = lane & 15, quad = lane >> 4;
    int bbase = (wg & 3) * 256 + wv * 64;
    const float invN1 = 1.f / (1024.f * 196.f);
    f16x8 a8, c8;
#pragma unroll
    for (int e = 0; e < 8; e++) {
        int ch = (quad & 1) * 8 + e;
        float s = acc1[ch], q = acc1[16 + ch];
        float m = s * invN1, var = q * invN1 - m * m;
        float r = rsqrtf(var + EPS);
        float av = g1[ch] * r;
        a8[e] = (_Float16)av;
        c8[e] = (_Float16)(be1[ch] - m * av);
    }
    f32x4 acc[2][4] = {};
#pragma unroll
    for (int t = 0; t < 5; t++) {
        int posA = 2 * t + (quad >> 1);         // 0..9 ; 9 hits W2h zero plane
        int posB = posA > 8 ? 8 : posA;         // B reads pos8 (A slot is zero)
        int ip = (i + posB / 3) * 14 + (j + posB % 3);
        f16x8 afr[2];
#pragma unroll
        for (int ot = 0; ot < 2; ot++)
            afr[ot] = *(const f16x8*)(W2h + (size_t)(p * 10 + posA) * 512 + (ot * 16 + n) * 16 + (quad & 1) * 8);
#pragma unroll
        for (int nt = 0; nt < 4; nt++) {
            f16x8 xv = *(const f16x8*)(act1h + ((size_t)(ip * 1024 + bbase + nt * 16 + n)) * 16 + (quad & 1) * 8);
#pragma unroll
            for (int e = 0; e < 8; e++) {
                _Float16 v = xv[e] * a8[e] + c8[e];
                xv[e] = v > (_Float16)0.f ? v : (_Float16)0.f;
            }
#pragma unroll
            for (int ot = 0; ot < 2; ot++)
                acc[ot][nt] = __builtin_amdgcn_mfma_f32_16x16x32_f16(afr[ot], xv, acc[ot][nt], 0, 0, 0);
        }
    }
    float s_[8] = {}, q_[8] = {};
#pragma unroll
    for (int ot = 0; ot < 2; ot++) {
        float bias[4];
#pragma unroll
        for (int r = 0; r < 4; r++) bias[r] = b2[(ot * 16 + quad * 4 + r) * 144 + p];
#pragma unroll
        for (int nt = 0; nt < 4; nt++) {
            int b = bbase + nt * 16 + n;
            f16x4 st;
#pragma unroll
            for (int r = 0; r < 4; r++) {
                float v = acc[ot][nt][r] + bias[r];
                st[r] = (_Float16)v;
                s_[ot * 4 + r] += v; q_[ot * 4 + r] += v * v;
            }
            *(f16x4*)(act2h + ((size_t)(p * 1024 + b)) * 32 + ot * 16 + quad * 4) = st;
        }
    }
    __shared__ float red[64 * 65];
#pragma unroll
    for (int u = 0; u < 8; u++) {
        int o = (u >> 2) * 16 + quad * 4 + (u & 3);
        red[(2 * o) * 65 + wv * 16 + n] = s_[u];
        red[(2 * o + 1) * 65 + wv * 16 + n] = q_[u];
    }
    __syncthreads();
    if (tid < 64) {
        const float* row = red + tid * 65;
        float t0 = 0.f;
#pragma unroll
        for (int c = 0; c < 64; c++) t0 += row[c];
        atomicAdd(acc2 + (tid & 1) * 32 + (tid >> 1), t0);
    }
}

// ---------------- LC3 MFMA: act2h (+BN2/ReLU on read) -> act3h RAW; stats -> atomicAdd acc3 ----------------
// grid: 400 blocks 1-D, XCD swizzle (400 = 8*50 -> 12-13 contiguous p per XCD; act2 halo ~2.9MB + W3 slice ~0.5MB fit 4MB L2)
__global__ __launch_bounds__(256) void k_lc3m(const _Float16* __restrict__ act2h,
                                              const _Float16* __restrict__ W3h,
                                              const float* __restrict__ b3,
                                              const float* __restrict__ acc2,  // s[32] q[32]
                                              const float* __restrict__ g2,
                                              const float* __restrict__ be2,
                                              _Float16* __restrict__ act3h,
                                              float* __restrict__ acc3) {      // s[64] q[64]
    int bid = blockIdx.x;
    int wg = (bid & 7) * 50 + (bid >> 3);
    int p = wg >> 2, i = p / 10, j = p % 10;
    int tid = threadIdx.x, wv = tid >> 6, lane = tid & 63, n = lane & 15, quad = lane >> 4;
    int bbase = (wg & 3) * 256 + wv * 64;
    const float invN2 = 1.f / (1024.f * 144.f);
    f16x8 a8, c8;
#pragma unroll
    for (int e = 0; e < 8; e++) {
        int ch = quad * 8 + e;
        float s = acc2[ch], q = acc2[32 + ch];
        float m = s * invN2, var = q * invN2 - m * m;
        float r = rsqrtf(var + EPS);
        float av = g2[ch] * r;
        a8[e] = (_Float16)av;
        c8[e] = (_Float16)(be2[ch] - m * av);
    }
    f32x4 acc[4][4] = {};
#pragma unroll
    for (int pos = 0; pos < 9; pos++) {
        int ip = (i + pos / 3) * 12 + (j + pos % 3);
        f16x8 afr[4];
#pragma unroll
        for (int ot = 0; ot < 4; ot++)
            afr[ot] = *(const f16x8*)(W3h + (size_t)(p * 9 + pos) * 2048 + (ot * 16 + n) * 32 + quad * 8);
#pragma unroll
        for (int nt = 0; nt < 4; nt++) {
            f16x8 xv = *(const f16x8*)(act2h + ((size_t)(ip * 1024 + bbase + nt * 16 + n)) * 32 + quad * 8);
#pragma unroll
            for (int e = 0; e < 8; e++) {
                _Float16 v = xv[e] * a8[e] + c8[e];
                xv[e] = v > (_Float16)0.f ? v : (_Float16)0.f;
            }
#pragma unroll
            for (int ot = 0; ot < 4; ot++)
                acc[ot][nt] = __builtin_amdgcn_mfma_f32_16x16x32_f16(afr[ot], xv, acc[ot][nt], 0, 0, 0);
        }
    }
    float s_[16] = {}, q_[16] = {};
#pragma unroll
    for (int ot = 0; ot < 4; ot++) {
        float bias[4];
#pragma unroll
        for (int r = 0; r < 4; r++) bias[r] = b3[(ot * 16 + quad * 4 + r) * 100 + p];
#pragma unroll
        for (int nt = 0; nt < 4; nt++) {
            int b = bbase + nt * 16 + n;
            f16x4 st;
#pragma unroll
            for (int r = 0; r < 4; r++) {
                float v = acc[ot][nt][r] + bias[r];
                st[r] = (_Float16)v;
                s_[ot * 4 + r] += v; q_[ot * 4 + r] += v * v;
            }
            *(f16x4*)(act3h + ((size_t)(p * 1024 + b)) * 64 + ot * 16 + quad * 4) = st;
        }
    }
    __shared__ float red[128 * 65];
#pragma unroll
    for (int u = 0; u < 16; u++) {
        int o = (u >> 2) * 16 + quad * 4 + (u & 3);
        red[(2 * o) * 65 + wv * 16 + n] = s_[u];
        red[(2 * o + 1) * 65 + wv * 16 + n] = q_[u];
    }
    __syncthreads();
    if (tid < 128) {
        const float* row = red + tid * 65;
        float t0 = 0.f;
#pragma unroll
        for (int c = 0; c < 64; c++) t0 += row[c];
        atomicAdd(acc3 + (tid & 1) * 64 + (tid >> 1), t0);
    }
}

// ---------------- FC: tanh(BN3(act3h)) @ fcW^T -> partials [p][jj][b] ----------------
__global__ __launch_bounds__(256) void k_fc(const _Float16* __restrict__ act3h,
                                            const float* __restrict__ fcW,
                                            const float* __restrict__ acc3,  // s[64] q[64]
                                            const float* __restrict__ g3,
                                            const float* __restrict__ be3,
                                            float* __restrict__ fpart) {
    int p = blockIdx.y;
    int tid = threadIdx.x;
    int b = blockIdx.x * 256 + tid;
    __shared__ float wS[640], aS[64], cS[64];
    for (int idx = tid; idx < 640; idx += 256) {
        int o = idx / 10, jj = idx % 10;
        wS[idx] = fcW[jj * 6400 + o * 100 + p];
    }
    if (tid < 64) {
        const float invN3 = 1.f / (1024.f * 100.f);
        float s = acc3[tid], q = acc3[64 + tid];
        float m = s * invN3, var = q * invN3 - m * m;
        float r = rsqrtf(var + EPS);
        float av = g3[tid] * r;
        aS[tid] = av; cS[tid] = be3[tid] - m * av;
    }
    __syncthreads();
    float acc[10];
#pragma unroll
    for (int jj = 0; jj < 10; jj++) acc[jj] = 0.f;
    const _Float16* src = act3h + ((size_t)(p * 1024 + b)) * 64;
    for (int o8 = 0; o8 < 8; o8++) {
        f16x8 xv = *(const f16x8*)(src + o8 * 8);
#pragma unroll
        for (int e = 0; e < 8; e++) {
            int o = o8 * 8 + e;
            float v = fmaf(aS[o], (float)xv[e], cS[o]);
            float e2 = __expf(2.f * v);
            v = 1.f - 2.f / (e2 + 1.f);   // tanh, safe at +/-inf
#pragma unroll
            for (int jj = 0; jj < 10; jj++) acc[jj] = fmaf(wS[o * 10 + jj], v, acc[jj]);
        }
    }
#pragma unroll
    for (int jj = 0; jj < 10; jj++) fpart[((size_t)p * 10 + jj) * 1024 + b] = acc[jj];
}

// ---------------- reduce fc partials + bias -> out ----------------
__global__ __launch_bounds__(256) void k_fc_reduce(const float* __restrict__ fpart,
                                                   const float* __restrict__ fcb,
                                                   float* __restrict__ out) {
    int idx = blockIdx.x * 256 + threadIdx.x;  // jj*1024 + b
    int jj = idx >> 10, b = idx & 1023;
    float acc = fcb[jj];
    for (int p = 0; p < 100; p++) acc += fpart[(p * 10 + jj) * 1024 + b];
    out[b * 10 + jj] = acc;
}

extern "C" void kernel_launch(void* const* d_in, const int* in_sizes, int n_in,
                              void* d_out, int out_size, void* d_ws, size_t ws_size,
                              hipStream_t stream) {
    const float* x   = (const float*)d_in[0];
    const float* W1  = (const float*)d_in[1];
    const float* b1  = (const float*)d_in[2];
    const float* g1  = (const float*)d_in[3];
    const float* be1 = (const float*)d_in[4];
    const float* W2  = (const float*)d_in[5];
    const float* b2  = (const float*)d_in[6];
    const float* g2  = (const float*)d_in[7];
    const float* be2 = (const float*)d_in[8];
    const float* W3  = (const float*)d_in[9];
    const float* b3  = (const float*)d_in[10];
    const float* g3  = (const float*)d_in[11];
    const float* be3 = (const float*)d_in[12];
    const float* fcW = (const float*)d_in[13];
    const float* fcb = (const float*)d_in[14];
    float* out = (float*)d_out;
    float* ws = (float*)d_ws;

    float* xT    = ws + XT_OFF;
    _Float16* act1h = (_Float16*)(ws + ACT1_OFF);
    _Float16* act2h = (_Float16*)(ws + ACT2_OFF);
    _Float16* act3h = (_Float16*)(ws + ACT3_OFF);
    _Float16* W2h   = (_Float16*)(ws + W2H_OFF);
    _Float16* W3h   = (_Float16*)(ws + W3H_OFF);
    float* fp   = ws + FP_OFF;
    float* acc  = ws + ACC_OFF;

    k_prep<<<3572, 256, 0, stream>>>(W2, W3, x, W2h, W3h, xT, acc);
    k_lc1<<<784, 256, 0, stream>>>(xT, W1, b1, act1h, acc);
    k_lc2m<<<576, 256, 0, stream>>>(act1h, W2h, b2, acc, g1, be1, act2h, acc + 32);
    k_lc3m<<<400, 256, 0, stream>>>(act2h, W3h, b3, acc + 32, g2, be2, act3h, acc + 96);
    k_fc<<<dim3(4, 100), 256, 0, stream>>>(act3h, fcW, acc + 96, g3, be3, fp);
    k_fc_reduce<<<40, 256, 0, stream>>>(fp, fcb, out);
}